// Round 1
// baseline (751.754 us; speedup 1.0000x reference)
//
#include <hip/hip_runtime.h>
#include <hip/hip_bf16.h>
#include <math.h>

#define HID 128
#define INDIM 256

// ---------------- edge dtype detection ----------------
// Reference declares edge_index int64, but JAX without x64 gives int32.
// If the buffer is really int64 (little-endian, values < 2^31), every odd
// int32 word is 0. Sampling 64 odd words: all-zero => int64. Data-driven,
// same work every call (graph-capture safe).
__global__ void detect_i64_kernel(const int* __restrict__ idx32, int* __restrict__ flag) {
    int l = threadIdx.x;             // 0..63
    int v = idx32[2 * l + 1];
    unsigned long long ball = __ballot(v != 0);
    if (l == 0) flag[0] = (ball == 0ULL) ? 1 : 0;
}

__device__ __forceinline__ int load_src(const int* idx, int is64, int E, int e) {
    return is64 ? idx[2 * e] : idx[e];
}
__device__ __forceinline__ int load_dst(const int* idx, int is64, int E, int e) {
    return is64 ? idx[2 * (E + e)] : idx[E + e];
}

// ---------------- CSR build ----------------
__global__ void hist_kernel(const int* __restrict__ idx32, const int* __restrict__ flag,
                            int* __restrict__ cnt, int E) {
    int is64 = flag[0];
    int i = blockIdx.x * blockDim.x + threadIdx.x;
    int stride = gridDim.x * blockDim.x;
    for (int e = i; e < E; e += stride) {
        int d = load_dst(idx32, is64, E, e);
        atomicAdd(&cnt[d], 1);
    }
}

// single-block scan over N counts -> rowstart (exclusive, N+1) and cursor (=rowstart[i])
__global__ __launch_bounds__(1024) void scan_kernel(const int* __restrict__ cnt,
                                                    int* __restrict__ rowstart,
                                                    int* __restrict__ cursor, int n) {
    __shared__ int wsum[16];
    __shared__ int sbase;
    int t = threadIdx.x;
    int lane = t & 63, w = t >> 6;
    if (t == 0) { sbase = 0; rowstart[0] = 0; }
    __syncthreads();
    for (int start = 0; start < n; start += 1024) {
        int i = start + t;
        int v = (i < n) ? cnt[i] : 0;
        int xv = v;
        #pragma unroll
        for (int off = 1; off < 64; off <<= 1) {
            int y = __shfl_up(xv, off);
            if (lane >= off) xv += y;
        }
        if (lane == 63) wsum[w] = xv;
        __syncthreads();
        if (w == 0 && lane < 16) {
            int s = wsum[lane];
            #pragma unroll
            for (int off = 1; off < 16; off <<= 1) {
                int y = __shfl_up(s, off);
                if (lane >= off) s += y;
            }
            wsum[lane] = s;                      // inclusive over wave sums
        }
        __syncthreads();
        int base = sbase;
        int waveoff = (w == 0) ? 0 : wsum[w - 1];
        int incl = base + waveoff + xv;          // inclusive prefix incl. v
        if (i < n) { rowstart[i + 1] = incl; cursor[i] = incl - v; }
        int total = wsum[15];
        __syncthreads();
        if (t == 0) sbase = base + total;
        // next iteration's reads of sbase occur after its first barrier -> safe
    }
}

__global__ void scatter_kernel(const int* __restrict__ idx32, const int* __restrict__ flag,
                               int* __restrict__ cursor, int* __restrict__ csr_src, int E) {
    int is64 = flag[0];
    int i = blockIdx.x * blockDim.x + threadIdx.x;
    int stride = gridDim.x * blockDim.x;
    for (int e = i; e < E; e += stride) {
        int s = load_src(idx32, is64, E, e);
        int d = load_dst(idx32, is64, E, e);
        int pos = atomicAdd(&cursor[d], 1);
        csr_src[pos] = s;
    }
}

// ---------------- encoder: h = relu(x @ W + b), x:(N,256) W:(256,128) ----------------
__global__ __launch_bounds__(256) void encoder_kernel(const float* __restrict__ x,
                                                      const float* __restrict__ W,
                                                      const float* __restrict__ b,
                                                      float* __restrict__ h, int N) {
    __shared__ float xs[64][36];   // stride 36 floats = 144B (16B aligned, bank-shifted)
    __shared__ float ws[32][128];
    int t = threadIdx.x;
    int n0 = blockIdx.x * 64;
    int tc = t & 15, tr = t >> 4;
    int c0 = tc * 8, r0 = tr * 4;
    float acc[4][8];
    #pragma unroll
    for (int i = 0; i < 4; i++)
        #pragma unroll
        for (int j = 0; j < 8; j++) acc[i][j] = 0.f;

    int lr = t >> 2, lc = (t & 3) * 8;     // x-tile load: 64 rows x 32 cols
    int wr = t >> 3, wc = (t & 7) * 16;    // W-tile load: 32 rows x 128 cols

    for (int k0 = 0; k0 < INDIM; k0 += 32) {
        int gr = n0 + lr; if (gr >= N) gr = N - 1;   // clamp (stores guarded)
        const float4* xg = (const float4*)(x + (size_t)gr * INDIM + k0 + lc);
        float4 a0 = xg[0], a1 = xg[1];
        *(float4*)&xs[lr][lc]     = a0;
        *(float4*)&xs[lr][lc + 4] = a1;
        const float4* wg = (const float4*)(W + (size_t)(k0 + wr) * HID + wc);
        float4 b0 = wg[0], b1 = wg[1], b2 = wg[2], b3 = wg[3];
        *(float4*)&ws[wr][wc]      = b0;
        *(float4*)&ws[wr][wc + 4]  = b1;
        *(float4*)&ws[wr][wc + 8]  = b2;
        *(float4*)&ws[wr][wc + 12] = b3;
        __syncthreads();
        #pragma unroll
        for (int kk = 0; kk < 32; ++kk) {
            float xv[4];
            #pragma unroll
            for (int i = 0; i < 4; i++) xv[i] = xs[r0 + i][kk];
            float4 w0 = *(float4*)&ws[kk][c0];
            float4 w1 = *(float4*)&ws[kk][c0 + 4];
            float wv[8] = {w0.x, w0.y, w0.z, w0.w, w1.x, w1.y, w1.z, w1.w};
            #pragma unroll
            for (int i = 0; i < 4; i++)
                #pragma unroll
                for (int j = 0; j < 8; j++)
                    acc[i][j] = fmaf(xv[i], wv[j], acc[i][j]);
        }
        __syncthreads();
    }
    #pragma unroll
    for (int i = 0; i < 4; i++) {
        int gr = n0 + r0 + i;
        if (gr < N) {
            #pragma unroll
            for (int j = 0; j < 8; j += 4) {
                float4 o;
                o.x = acc[i][j + 0] + b[c0 + j + 0];
                o.y = acc[i][j + 1] + b[c0 + j + 1];
                o.z = acc[i][j + 2] + b[c0 + j + 2];
                o.w = acc[i][j + 3] + b[c0 + j + 3];
                o.x = o.x > 0.f ? o.x : 0.f;
                o.y = o.y > 0.f ? o.y : 0.f;
                o.z = o.z > 0.f ? o.z : 0.f;
                o.w = o.w > 0.f ? o.w : 0.f;
                *(float4*)(h + (size_t)gr * HID + c0 + j) = o;
            }
        }
    }
}

// ---------------- per-node attention projections ----------------
// ai[n] = h[n].wi + b   (dst side, bias folded), aj[n] = h[n].wj  (src side)
__global__ __launch_bounds__(256) void attproj_kernel(const float* __restrict__ h,
                                                      const float* __restrict__ attw,
                                                      const float* __restrict__ attb,
                                                      float* __restrict__ ai,
                                                      float* __restrict__ aj, int N) {
    int t = threadIdx.x;
    int lane = t & 63, w = t >> 6;
    int n = blockIdx.x * 4 + w;
    if (n >= N) return;
    const float2* h2 = (const float2*)(h + (size_t)n * HID);
    float2 hv = h2[lane];
    float wi0 = attw[2 * lane], wi1 = attw[2 * lane + 1];
    float wj0 = attw[HID + 2 * lane], wj1 = attw[HID + 2 * lane + 1];
    float pi = hv.x * wi0 + hv.y * wi1;
    float pj = hv.x * wj0 + hv.y * wj1;
    #pragma unroll
    for (int off = 32; off >= 1; off >>= 1) {
        pi += __shfl_xor(pi, off);
        pj += __shfl_xor(pj, off);
    }
    if (lane == 0) { ai[n] = pi + attb[0]; aj[n] = pj; }
}

// ---------------- care aggregation: one wave per dst node ----------------
// MODE 0: out = relu(sums/max(cnt,1))  (N,128)
// MODE 1: out = (sums/max(cnt,1)) @ cls_w + cls_b   (N,2), classifier fused
template <int MODE>
__global__ __launch_bounds__(256) void care_kernel(const float* __restrict__ h,
                                                   const float* __restrict__ ai,
                                                   const float* __restrict__ aj,
                                                   const int* __restrict__ rowstart,
                                                   const int* __restrict__ csr_src,
                                                   float* __restrict__ out, int N,
                                                   const float* __restrict__ clsw,
                                                   const float* __restrict__ clsb) {
    int t = threadIdx.x;
    int lane = t & 63, w = t >> 6;
    int n = blockIdx.x * 4 + w;
    if (n >= N) return;
    int beg = rowstart[n], end = rowstart[n + 1];
    float ain = ai[n];
    const float2* h2 = (const float2*)h;
    float acc0 = 0.f, acc1 = 0.f;
    for (int e = beg; e < end; ++e) {
        int s = csr_src[e];
        float a = ain + aj[s];
        float alpha = 1.0f / (1.0f + __expf(-a));
        float2 hv = h2[(size_t)s * (HID / 2) + lane];
        acc0 = fmaf(alpha, hv.x, acc0);
        acc1 = fmaf(alpha, hv.y, acc1);
    }
    float scale = 1.0f / fmaxf((float)(end - beg), 1.0f);
    acc0 *= scale;
    acc1 *= scale;
    if (MODE == 0) {
        float2 o;
        o.x = acc0 > 0.f ? acc0 : 0.f;
        o.y = acc1 > 0.f ? acc1 : 0.f;
        ((float2*)out)[(size_t)n * (HID / 2) + lane] = o;
    } else {
        float w00 = clsw[(2 * lane) * 2 + 0], w01 = clsw[(2 * lane) * 2 + 1];
        float w10 = clsw[(2 * lane + 1) * 2 + 0], w11 = clsw[(2 * lane + 1) * 2 + 1];
        float p0 = acc0 * w00 + acc1 * w10;
        float p1 = acc0 * w01 + acc1 * w11;
        #pragma unroll
        for (int off = 32; off >= 1; off >>= 1) {
            p0 += __shfl_xor(p0, off);
            p1 += __shfl_xor(p1, off);
        }
        if (lane == 0) {
            out[(size_t)n * 2 + 0] = p0 + clsb[0];
            out[(size_t)n * 2 + 1] = p1 + clsb[1];
        }
    }
}

extern "C" void kernel_launch(void* const* d_in, const int* in_sizes, int n_in,
                              void* d_out, int out_size, void* d_ws, size_t ws_size,
                              hipStream_t stream) {
    const float* x      = (const float*)d_in[0];
    const int*   idx32  = (const int*)d_in[1];
    const float* enc_w  = (const float*)d_in[2];
    const float* enc_b  = (const float*)d_in[3];
    const float* att1_w = (const float*)d_in[4];
    const float* att1_b = (const float*)d_in[5];
    const float* att2_w = (const float*)d_in[6];
    const float* att2_b = (const float*)d_in[7];
    const float* cls_w  = (const float*)d_in[8];
    const float* cls_b  = (const float*)d_in[9];
    float* out = (float*)d_out;

    int N = in_sizes[0] / INDIM;      // 50000
    int E = in_sizes[1] / 2;          // 1.6M

    // workspace carve-up (~58.5 MB total)
    char* p = (char*)d_ws;
    float* h1   = (float*)p; p += (size_t)N * HID * 4;
    float* hmid = (float*)p; p += (size_t)N * HID * 4;
    int* csr_src  = (int*)p; p += (size_t)E * 4;
    float* ai   = (float*)p; p += (size_t)N * 4;
    float* aj   = (float*)p; p += (size_t)N * 4;
    int* cnt      = (int*)p; p += (size_t)N * 4;
    int* rowstart = (int*)p; p += (size_t)(N + 1) * 4;
    int* cursor   = (int*)p; p += (size_t)N * 4;
    int* flag     = (int*)p; p += 64;

    hipMemsetAsync(cnt, 0, (size_t)N * 4, stream);
    detect_i64_kernel<<<1, 64, 0, stream>>>(idx32, flag);
    hist_kernel<<<1024, 256, 0, stream>>>(idx32, flag, cnt, E);
    scan_kernel<<<1, 1024, 0, stream>>>(cnt, rowstart, cursor, N);
    scatter_kernel<<<1024, 256, 0, stream>>>(idx32, flag, cursor, csr_src, E);

    encoder_kernel<<<(N + 63) / 64, 256, 0, stream>>>(x, enc_w, enc_b, h1, N);

    attproj_kernel<<<(N + 3) / 4, 256, 0, stream>>>(h1, att1_w, att1_b, ai, aj, N);
    care_kernel<0><<<(N + 3) / 4, 256, 0, stream>>>(h1, ai, aj, rowstart, csr_src,
                                                    hmid, N, nullptr, nullptr);
    attproj_kernel<<<(N + 3) / 4, 256, 0, stream>>>(hmid, att2_w, att2_b, ai, aj, N);
    care_kernel<1><<<(N + 3) / 4, 256, 0, stream>>>(hmid, ai, aj, rowstart, csr_src,
                                                    out, N, cls_w, cls_b);
}

// Round 2
// 490.089 us; speedup vs baseline: 1.5339x; 1.5339x over previous
//
#include <hip/hip_runtime.h>
#include <hip/hip_bf16.h>
#include <hip/hip_fp16.h>
#include <math.h>

#define HID 128
#define INDIM 256

// ---------------- edge dtype detection ----------------
// Reference declares edge_index int64, but JAX without x64 gives int32.
// If the buffer is really int64 (LE, values < 2^31), every odd int32 word is 0.
__global__ void detect_i64_kernel(const int* __restrict__ idx32, int* __restrict__ flag) {
    int l = threadIdx.x;             // 0..63
    int v = idx32[2 * l + 1];
    unsigned long long ball = __ballot(v != 0);
    if (l == 0) flag[0] = (ball == 0ULL) ? 1 : 0;
}

__device__ __forceinline__ int load_src(const int* idx, int is64, int E, int e) {
    return is64 ? idx[2 * e] : idx[e];
}
__device__ __forceinline__ int load_dst(const int* idx, int is64, int E, int e) {
    return is64 ? idx[2 * (E + e)] : idx[E + e];
}

// ---------------- CSR build ----------------
__global__ void hist_kernel(const int* __restrict__ idx32, const int* __restrict__ flag,
                            int* __restrict__ cnt, int E) {
    int is64 = flag[0];
    int i = blockIdx.x * blockDim.x + threadIdx.x;
    int stride = gridDim.x * blockDim.x;
    for (int e = i; e < E; e += stride) {
        int d = load_dst(idx32, is64, E, e);
        atomicAdd(&cnt[d], 1);
    }
}

// block-level inclusive scan helper (256 threads, 4 waves)
__device__ __forceinline__ int block_incl_scan(int v, int t, int* ws) {
    int lane = t & 63, w = t >> 6;
    int x = v;
    #pragma unroll
    for (int off = 1; off < 64; off <<= 1) {
        int y = __shfl_up(x, off);
        if (lane >= off) x += y;
    }
    if (lane == 63) ws[w] = x;
    __syncthreads();
    if (t == 0) {
        int s = 0;
        #pragma unroll
        for (int k = 0; k < 4; k++) { int y = ws[k]; ws[k] = s; s += y; }
    }
    __syncthreads();
    return x + ws[w];
}

// phase 1: per-256-chunk inclusive scan + chunk totals
__global__ __launch_bounds__(256) void scan_block_kernel(const int* __restrict__ cnt,
                                                         int* __restrict__ incl,
                                                         int* __restrict__ bsum, int n) {
    __shared__ int ws[4];
    int t = threadIdx.x;
    int i = blockIdx.x * 256 + t;
    int v = (i < n) ? cnt[i] : 0;
    int x = block_incl_scan(v, t, ws);
    if (i < n) incl[i] = x;
    if (t == 255) bsum[blockIdx.x] = x;
}

// phase 2: single-block exclusive scan of chunk totals (nb <= 256)
__global__ __launch_bounds__(256) void scan_top_kernel(int* __restrict__ bsum, int nb) {
    __shared__ int ws[4];
    int t = threadIdx.x;
    int v = (t < nb) ? bsum[t] : 0;
    int x = block_incl_scan(v, t, ws);
    if (t < nb) bsum[t] = x - v;   // exclusive
}

// phase 3: rowstart / cursor
__global__ __launch_bounds__(256) void scan_finish_kernel(const int* __restrict__ incl,
                                                          const int* __restrict__ cnt,
                                                          const int* __restrict__ bsum,
                                                          int* __restrict__ rowstart,
                                                          int* __restrict__ cursor, int n) {
    int i = blockIdx.x * 256 + threadIdx.x;
    if (i < n) {
        int inc = incl[i] + bsum[i >> 8];
        rowstart[i + 1] = inc;
        cursor[i] = inc - cnt[i];
        if (i == 0) rowstart[0] = 0;
    }
}

__global__ void scatter_kernel(const int* __restrict__ idx32, const int* __restrict__ flag,
                               int* __restrict__ cursor, int* __restrict__ csr_src, int E) {
    int is64 = flag[0];
    int i = blockIdx.x * blockDim.x + threadIdx.x;
    int stride = gridDim.x * blockDim.x;
    for (int e = i; e < E; e += stride) {
        int s = load_src(idx32, is64, E, e);
        int d = load_dst(idx32, is64, E, e);
        int pos = atomicAdd(&cursor[d], 1);
        csr_src[pos] = s;
    }
}

// ---------------- encoder: h16 = relu(x @ W + b) in fp16, x:(N,256) W:(256,128) ----------------
__global__ __launch_bounds__(256) void encoder_kernel(const float* __restrict__ x,
                                                      const float* __restrict__ W,
                                                      const float* __restrict__ b,
                                                      __half* __restrict__ h16, int N) {
    __shared__ float xs[64][36];   // stride 36 floats (16B aligned, bank-shifted)
    __shared__ float ws[32][128];
    int t = threadIdx.x;
    int n0 = blockIdx.x * 64;
    int tc = t & 15, tr = t >> 4;
    int c0 = tc * 8, r0 = tr * 4;
    float acc[4][8];
    #pragma unroll
    for (int i = 0; i < 4; i++)
        #pragma unroll
        for (int j = 0; j < 8; j++) acc[i][j] = 0.f;

    int lr = t >> 2, lc = (t & 3) * 8;     // x-tile load: 64 rows x 32 cols
    int wr = t >> 3, wc = (t & 7) * 16;    // W-tile load: 32 rows x 128 cols

    for (int k0 = 0; k0 < INDIM; k0 += 32) {
        int gr = n0 + lr; if (gr >= N) gr = N - 1;
        const float4* xg = (const float4*)(x + (size_t)gr * INDIM + k0 + lc);
        float4 a0 = xg[0], a1 = xg[1];
        *(float4*)&xs[lr][lc]     = a0;
        *(float4*)&xs[lr][lc + 4] = a1;
        const float4* wg = (const float4*)(W + (size_t)(k0 + wr) * HID + wc);
        float4 b0 = wg[0], b1 = wg[1], b2 = wg[2], b3 = wg[3];
        *(float4*)&ws[wr][wc]      = b0;
        *(float4*)&ws[wr][wc + 4]  = b1;
        *(float4*)&ws[wr][wc + 8]  = b2;
        *(float4*)&ws[wr][wc + 12] = b3;
        __syncthreads();
        #pragma unroll
        for (int kk = 0; kk < 32; ++kk) {
            float xv[4];
            #pragma unroll
            for (int i = 0; i < 4; i++) xv[i] = xs[r0 + i][kk];
            float4 w0 = *(float4*)&ws[kk][c0];
            float4 w1 = *(float4*)&ws[kk][c0 + 4];
            float wv[8] = {w0.x, w0.y, w0.z, w0.w, w1.x, w1.y, w1.z, w1.w};
            #pragma unroll
            for (int i = 0; i < 4; i++)
                #pragma unroll
                for (int j = 0; j < 8; j++)
                    acc[i][j] = fmaf(xv[i], wv[j], acc[i][j]);
        }
        __syncthreads();
    }
    #pragma unroll
    for (int i = 0; i < 4; i++) {
        int gr = n0 + r0 + i;
        if (gr < N) {
            union { float4 f; __half2 h[4]; } u;
            #pragma unroll
            for (int j = 0; j < 8; j += 2) {
                float o0 = acc[i][j + 0] + b[c0 + j + 0];
                float o1 = acc[i][j + 1] + b[c0 + j + 1];
                o0 = o0 > 0.f ? o0 : 0.f;
                o1 = o1 > 0.f ? o1 : 0.f;
                u.h[j >> 1] = __float22half2_rn(make_float2(o0, o1));
            }
            *(float4*)(h16 + (size_t)gr * HID + c0) = u.f;
        }
    }
}

// ---------------- per-node attention projections (from fp16 h) ----------------
__global__ __launch_bounds__(256) void attproj_kernel(const __half* __restrict__ hh,
                                                      const float* __restrict__ attw,
                                                      const float* __restrict__ attb,
                                                      float* __restrict__ ai,
                                                      float* __restrict__ aj, int N) {
    int t = threadIdx.x;
    int lane = t & 63, w = t >> 6;
    int n = blockIdx.x * 4 + w;
    if (n >= N) return;
    __half2 hv = ((const __half2*)hh)[(size_t)n * 64 + lane];
    float2 f = __half22float2(hv);
    float wi0 = attw[2 * lane], wi1 = attw[2 * lane + 1];
    float wj0 = attw[HID + 2 * lane], wj1 = attw[HID + 2 * lane + 1];
    float pi = f.x * wi0 + f.y * wi1;
    float pj = f.x * wj0 + f.y * wj1;
    #pragma unroll
    for (int off = 32; off >= 1; off >>= 1) {
        pi += __shfl_xor(pi, off);
        pj += __shfl_xor(pj, off);
    }
    if (lane == 0) { ai[n] = pi + attb[0]; aj[n] = pj; }
}

// ---------------- care aggregation: one wave per dst, 4 edge-groups x 16 feature-lanes ----
// MODE 0: hh_out = (fp16) relu(sums/max(cnt,1))
// MODE 1: out = (sums/max(cnt,1)) @ cls_w + cls_b   (N,2), classifier fused
template <int MODE>
__global__ __launch_bounds__(256) void care_kernel(const __half* __restrict__ hh,
                                                   const float* __restrict__ ai,
                                                   const float* __restrict__ aj,
                                                   const int* __restrict__ rowstart,
                                                   const int* __restrict__ csr_src,
                                                   float* __restrict__ out,
                                                   __half* __restrict__ hh_out, int N,
                                                   const float* __restrict__ clsw,
                                                   const float* __restrict__ clsb) {
    int t = threadIdx.x;
    int lane = t & 63, w = t >> 6;
    int n = blockIdx.x * 4 + w;
    if (n >= N) return;
    int beg = rowstart[n], end = rowstart[n + 1];
    int deg = end - beg;
    float ain = ai[n];
    int g = lane >> 4;        // edge subgroup 0..3
    int r = lane & 15;        // feature lane: features 8r..8r+7

    float acc[8];
    #pragma unroll
    for (int k = 0; k < 8; k++) acc[k] = 0.f;

    int nit = (deg + 3) >> 2;
    const float4* hp = (const float4*)hh;   // 16 float4 per row
    #pragma unroll 2
    for (int it = 0; it < nit; ++it) {
        int e = beg + it * 4 + g;
        int ee = (e < end) ? e : beg;
        int s = csr_src[ee];
        float a = ain + aj[s];
        float alpha = (e < end) ? (1.0f / (1.0f + __expf(-a))) : 0.f;
        float4 hv = hp[(size_t)s * 16 + r];
        union { float4 f; __half2 h[4]; } u; u.f = hv;
        #pragma unroll
        for (int k = 0; k < 4; k++) {
            float2 fv = __half22float2(u.h[k]);
            acc[2 * k + 0] = fmaf(alpha, fv.x, acc[2 * k + 0]);
            acc[2 * k + 1] = fmaf(alpha, fv.y, acc[2 * k + 1]);
        }
    }
    // combine the 4 edge-groups (lanes r, r+16, r+32, r+48)
    #pragma unroll
    for (int k = 0; k < 8; k++) {
        acc[k] += __shfl_xor(acc[k], 16);
        acc[k] += __shfl_xor(acc[k], 32);
    }
    float scale = 1.0f / fmaxf((float)deg, 1.0f);

    if (MODE == 0) {
        if (g == 0) {
            union { float4 f; __half2 h[4]; } u;
            #pragma unroll
            for (int k = 0; k < 4; k++) {
                float o0 = acc[2 * k + 0] * scale;
                float o1 = acc[2 * k + 1] * scale;
                o0 = o0 > 0.f ? o0 : 0.f;
                o1 = o1 > 0.f ? o1 : 0.f;
                u.h[k] = __float22half2_rn(make_float2(o0, o1));
            }
            ((float4*)hh_out)[(size_t)n * 16 + r] = u.f;
        }
    } else {
        float p0 = 0.f, p1 = 0.f;
        #pragma unroll
        for (int k = 0; k < 8; k++) {
            float m = acc[k] * scale;
            int f = r * 8 + k;
            p0 = fmaf(m, clsw[f * 2 + 0], p0);
            p1 = fmaf(m, clsw[f * 2 + 1], p1);
        }
        #pragma unroll
        for (int off = 8; off >= 1; off >>= 1) {
            p0 += __shfl_xor(p0, off);
            p1 += __shfl_xor(p1, off);
        }
        if (lane == 0) {
            out[(size_t)n * 2 + 0] = p0 + clsb[0];
            out[(size_t)n * 2 + 1] = p1 + clsb[1];
        }
    }
}

extern "C" void kernel_launch(void* const* d_in, const int* in_sizes, int n_in,
                              void* d_out, int out_size, void* d_ws, size_t ws_size,
                              hipStream_t stream) {
    const float* x      = (const float*)d_in[0];
    const int*   idx32  = (const int*)d_in[1];
    const float* enc_w  = (const float*)d_in[2];
    const float* enc_b  = (const float*)d_in[3];
    const float* att1_w = (const float*)d_in[4];
    const float* att1_b = (const float*)d_in[5];
    const float* att2_w = (const float*)d_in[6];
    const float* att2_b = (const float*)d_in[7];
    const float* cls_w  = (const float*)d_in[8];
    const float* cls_b  = (const float*)d_in[9];
    float* out = (float*)d_out;

    int N = in_sizes[0] / INDIM;      // 50000
    int E = in_sizes[1] / 2;          // 1.6M
    int NB = (N + 255) / 256;         // scan chunks (196)

    // workspace carve-up (~33 MB)
    char* p = (char*)d_ws;
    __half* h16a = (__half*)p; p += (size_t)N * HID * 2;
    __half* h16b = (__half*)p; p += (size_t)N * HID * 2;
    int* csr_src  = (int*)p; p += (size_t)E * 4;
    float* ai   = (float*)p; p += (size_t)N * 4;
    float* aj   = (float*)p; p += (size_t)N * 4;
    int* cnt      = (int*)p; p += (size_t)N * 4;
    int* incl     = (int*)p; p += (size_t)N * 4;
    int* rowstart = (int*)p; p += (size_t)(N + 1) * 4;
    int* cursor   = (int*)p; p += (size_t)N * 4;
    int* bsum     = (int*)p; p += 256 * 4;
    int* flag     = (int*)p; p += 64;

    hipMemsetAsync(cnt, 0, (size_t)N * 4, stream);
    detect_i64_kernel<<<1, 64, 0, stream>>>(idx32, flag);
    hist_kernel<<<1024, 256, 0, stream>>>(idx32, flag, cnt, E);
    scan_block_kernel<<<NB, 256, 0, stream>>>(cnt, incl, bsum, N);
    scan_top_kernel<<<1, 256, 0, stream>>>(bsum, NB);
    scan_finish_kernel<<<NB, 256, 0, stream>>>(incl, cnt, bsum, rowstart, cursor, N);
    scatter_kernel<<<1024, 256, 0, stream>>>(idx32, flag, cursor, csr_src, E);

    encoder_kernel<<<(N + 63) / 64, 256, 0, stream>>>(x, enc_w, enc_b, h16a, N);

    attproj_kernel<<<(N + 3) / 4, 256, 0, stream>>>(h16a, att1_w, att1_b, ai, aj, N);
    care_kernel<0><<<(N + 3) / 4, 256, 0, stream>>>(h16a, ai, aj, rowstart, csr_src,
                                                    nullptr, h16b, N, nullptr, nullptr);
    attproj_kernel<<<(N + 3) / 4, 256, 0, stream>>>(h16b, att2_w, att2_b, ai, aj, N);
    care_kernel<1><<<(N + 3) / 4, 256, 0, stream>>>(h16b, ai, aj, rowstart, csr_src,
                                                    out, nullptr, N, cls_w, cls_b);
}